// Round 12
// baseline (45.552 us; speedup 1.0000x reference)
//
#include <hip/hip_runtime.h>
#include <cmath>

namespace {

typedef _Float16 h8 __attribute__((ext_vector_type(8)));
typedef _Float16 h2 __attribute__((ext_vector_type(2)));
typedef __fp16   fp2 __attribute__((ext_vector_type(2)));   // cvt_pkrtz native type
typedef _Float16 h4 __attribute__((ext_vector_type(4)));

constexpr int C_     = 64;
constexpr int L_     = 32768;
constexpr int TILE   = 8192;
constexpr int HALO   = 776;           // receptive field 765, rounded to unit-8
constexpr int NB     = TILE + HALO;   // 8968 halfs
constexpr int NU     = NB / 8;        // 1121 h8 units
constexpr int HALO_U = HALO / 8;      // 97
constexpr int NT     = L_ / TILE;     // 4 tiles per row
constexpr int BLK    = 512;
constexpr int S2N    = NU - 2 * BLK;  // 97: threads owning a third unit

__device__ __forceinline__ h8 ld8(const _Float16* p) { return *reinterpret_cast<const h8*>(p); }
__device__ __forceinline__ void st8(_Float16* p, h8 v) { *reinterpret_cast<h8*>(p) = v; }
__device__ __forceinline__ float4 ld4f(const float* p) { return *reinterpret_cast<const float4*>(p); }
__device__ __forceinline__ void st4f(float* p, float4 v) { *reinterpret_cast<float4*>(p) = v; }
__device__ __forceinline__ h8 sp8(_Float16 v) { return (h8){v,v,v,v,v,v,v,v}; }

// Guaranteed v_pk_fma_f16 (r10: +5% vs mul/add trees).
__device__ __forceinline__ h8 fma8(h8 a, h8 b, h8 c) {
    return __builtin_elementwise_fma(a, b, c);
}

template<int K>
__device__ __forceinline__ h8 shconc(h8 A, h8 B) {
    return __builtin_shufflevector(A, B, K, K+1, K+2, K+3, K+4, K+5, K+6, K+7);
}

// f32x8 -> fp16x8 via v_cvt_pkrtz_f16_f32 (1 instr / 2 elems). The builtin
// returns __fp16x2; bit_cast to our _Float16x2.
__device__ __forceinline__ h2 pkrtz(float lo, float hi) {
    const fp2 r = __builtin_amdgcn_cvt_pkrtz(lo, hi);
    return __builtin_bit_cast(h2, r);
}
__device__ __forceinline__ h8 pack8(float4 a, float4 b) {
    const h2 p0 = pkrtz(a.x, a.y);
    const h2 p1 = pkrtz(a.z, a.w);
    const h2 p2 = pkrtz(b.x, b.y);
    const h2 p3 = pkrtz(b.z, b.w);
    return (h8){p0[0], p0[1], p1[0], p1[1], p2[0], p2[1], p3[0], p3[1]};
}

// tanh-form GELU: v * sigmoid(1.5958*v + 0.07135*v^3); absmax-verified vs erf
// across seven rounds (identical 0.0078125 overall absmax).
__device__ __forceinline__ float gelu_f(float v) {
    const float z = v * (1.5957691216057308f + 0.0713548162726f * v * v);
    const float e = __expf(-z);
    return v * __builtin_amdgcn_rcpf(1.0f + e);
}

// Tap gather + two 4-tap dot products for one unit of one level.
template<int D, bool LAST>
__device__ __forceinline__ void unit_math(const _Float16* __restrict__ src,
                                          int p, h8& lwv, h8& yv, bool doY,
                                          const _Float16* c1, const _Float16* c0)
{
    const h8 T3 = lwv;
    h8 T0, T1, T2;
    if constexpr (D == 1) {
        const h8 Lv = ld8(&src[p - 8]);
        T0 = shconc<5>(Lv, T3); T1 = shconc<6>(Lv, T3); T2 = shconc<7>(Lv, T3);
    } else if constexpr (D == 2) {
        const h8 Lv = ld8(&src[p - 8]);
        T0 = shconc<2>(Lv, T3); T1 = shconc<4>(Lv, T3); T2 = shconc<6>(Lv, T3);
    } else if constexpr (D == 4) {
        const h8 Lv = ld8(&src[p - 8]);
        const h8 LL = ld8(&src[p - 16]);
        T0 = shconc<4>(LL, Lv); T1 = Lv; T2 = shconc<4>(Lv, T3);
    } else {
        T0 = ld8(&src[p - 3 * D]);
        T1 = ld8(&src[p - 2 * D]);
        T2 = ld8(&src[p - D]);
    }
    if (doY) {
        h8 yt = yv;
        yt = fma8(sp8(c1[0]), T0, yt);
        yt = fma8(sp8(c1[1]), T1, yt);
        yt = fma8(sp8(c1[2]), T2, yt);
        yt = fma8(sp8(c1[3]), T3, yt);
        yv = yt;
    }
    h8 nl = sp8(c0[0]) * T0;
    nl = fma8(sp8(c0[1]), T1, nl);
    nl = fma8(sp8(c0[2]), T2, nl);
    nl = fma8(sp8(c0[3]), T3, nl);
    if constexpr (LAST) yv += nl;      // c0 pre-folded with w0
    else lwv = nl;
}

// One level, dilation D, 3 compile-time-specialized slots:
//  slot0 (un=tid     in [0,512)):    guard tid>=STARTU; y iff tid>=HALO_U.
//  slot1 (un=tid+512 in [512,1024)): unconditional (>=97, <NU, y always).
//  slot2 (un=tid+1024): exists iff tid<S2N=97; y always.
// Frontier recursion (correctness-proven r3..r10): STARTU per level
// 1,2,4,7,13,25,49,97; valid unit g at level D reads down to g-3D/8 >= prev
// STARTU, so below-frontier garbage is never read. Guards bound live ranges
// (r4-r7: unguarded variants -> 188 VGPR or scratch demotion).
template<int D, int STARTU, bool LAST>
__device__ __forceinline__ void level_pass(const _Float16* __restrict__ src,
                                           _Float16* __restrict__ dst,
                                           const float* h0f, const float* h1f,
                                           float wi, float w0,
                                           h8* lw, h8* yacc, int tid)
{
    _Float16 c1[4], c0[4];
#pragma unroll
    for (int t = 0; t < 4; ++t) {
        c1[t] = (_Float16)(wi * h1f[t]);
        c0[t] = (_Float16)(LAST ? w0 * h0f[t] : h0f[t]);
    }
    if (tid >= STARTU) {
        unit_math<D, LAST>(src, 8 * tid, lw[0], yacc[0], tid >= HALO_U, c1, c0);
        if constexpr (!LAST) st8(&dst[8 * tid], lw[0]);
    }
    {
        unit_math<D, LAST>(src, 8 * (tid + BLK), lw[1], yacc[1], true, c1, c0);
        if constexpr (!LAST) st8(&dst[8 * (tid + BLK)], lw[1]);
    }
    if (tid < S2N) {
        unit_math<D, LAST>(src, 8 * (tid + 2 * BLK), lw[2], yacc[2], true, c1, c0);
        if constexpr (!LAST) st8(&dst[8 * (tid + 2 * BLK)], lw[2]);
    }
}

// min-waves=8/SIMD (VGPR cap 64): guarded structure measured 24 VGPR — 2.6x
// headroom. LDS 2x17936B -> 4 blocks/CU x 8 waves = 32 waves/CU.
__global__ __launch_bounds__(BLK, 8)
void cmrc_kernel(const float* __restrict__ x,
                 const float* __restrict__ h0,
                 const float* __restrict__ h1,
                 const float* __restrict__ w,
                 float* __restrict__ out)
{
    __shared__ alignas(16) _Float16 buf[2][NB];

    const int tid  = threadIdx.x;
    const int blk  = blockIdx.x;
    const int tile = blk % NT;
    const int bc   = blk / NT;            // b*C + c
    const int c    = bc % C_;
    const long row = (long)bc * L_;
    const int  t0  = tile * TILE - HALO;  // global pos of buffer p=0

    float h0v[4], h1v[4];
#pragma unroll
    for (int k = 0; k < 4; ++k) { h0v[k] = h0[c*4+k]; h1v[k] = h1[c*4+k]; }
    float wv[10];
#pragma unroll
    for (int i = 0; i < 10; ++i) wv[i] = w[c*10+i];

    h8 lw[3];     // running low residual (own units, registers)
    h8 yacc[3];   // packed y accumulator

    const _Float16 w9h = (_Float16)wv[9];

    // ---- Stage x as fp16; init lw = x, y = w9*x ----
    // slot0: t<0 possible (tile 0) -> zero-fill guard (t is a multiple of 8).
    {
        const int t = t0 + 8 * tid;
        float4 xa = make_float4(0.f,0.f,0.f,0.f), xb = xa;
        if (t >= 0) { xa = ld4f(&x[row + t]); xb = ld4f(&x[row + t + 4]); }
        const h8 hv = pack8(xa, xb);
        st8(&buf[0][8 * tid], hv);
        lw[0] = hv;
        yacc[0] = sp8(w9h) * hv;           // only read back for tid>=HALO_U
    }
    // slot1: un in [512,1024): t >= 4096-776 > 0, t+7 < L -> unconditional.
    {
        const int t = t0 + 8 * (tid + BLK);
        const h8 hv = pack8(ld4f(&x[row + t]), ld4f(&x[row + t + 4]));
        st8(&buf[0][8 * (tid + BLK)], hv);
        lw[1] = hv;
        yacc[1] = sp8(w9h) * hv;
    }
    // slot2 (tid<97): un in [1024,1121): t in-range always.
    if (tid < S2N) {
        const int t = t0 + 8 * (tid + 2 * BLK);
        const h8 hv = pack8(ld4f(&x[row + t]), ld4f(&x[row + t + 4]));
        st8(&buf[0][8 * (tid + 2 * BLK)], hv);
        lw[2] = hv;
        yacc[2] = sp8(w9h) * hv;
    }
    __syncthreads();

    level_pass<1,   1,  false>(buf[0], buf[1], h0v, h1v, wv[8], 0.f, lw, yacc, tid); __syncthreads();
    level_pass<2,   2,  false>(buf[1], buf[0], h0v, h1v, wv[7], 0.f, lw, yacc, tid); __syncthreads();
    level_pass<4,   4,  false>(buf[0], buf[1], h0v, h1v, wv[6], 0.f, lw, yacc, tid); __syncthreads();
    level_pass<8,   7,  false>(buf[1], buf[0], h0v, h1v, wv[5], 0.f, lw, yacc, tid); __syncthreads();
    level_pass<16,  13, false>(buf[0], buf[1], h0v, h1v, wv[4], 0.f, lw, yacc, tid); __syncthreads();
    level_pass<32,  25, false>(buf[1], buf[0], h0v, h1v, wv[3], 0.f, lw, yacc, tid); __syncthreads();
    level_pass<64,  49, false>(buf[0], buf[1], h0v, h1v, wv[2], 0.f, lw, yacc, tid); __syncthreads();
    level_pass<128, 97, true >(buf[1], buf[0], h0v, h1v, wv[1], wv[0], lw, yacc, tid);

    // ---- Epilogue: fp32 GELU, two float4 stores per unit ----
    auto emit = [&](int un, h8 v) {
        float4 oa, ob;
        oa.x = gelu_f((float)v[0]); oa.y = gelu_f((float)v[1]);
        oa.z = gelu_f((float)v[2]); oa.w = gelu_f((float)v[3]);
        ob.x = gelu_f((float)v[4]); ob.y = gelu_f((float)v[5]);
        ob.z = gelu_f((float)v[6]); ob.w = gelu_f((float)v[7]);
        const long idx = row + (t0 + 8 * un);
        st4f(&out[idx], oa);
        st4f(&out[idx + 4], ob);
    };
    if (tid >= HALO_U) emit(tid, yacc[0]);
    emit(tid + BLK, yacc[1]);
    if (tid < S2N) emit(tid + 2 * BLK, yacc[2]);
}

}  // namespace

extern "C" void kernel_launch(void* const* d_in, const int* in_sizes, int n_in,
                              void* d_out, int out_size, void* d_ws, size_t ws_size,
                              hipStream_t stream)
{
    const float* x  = (const float*)d_in[0];
    const float* h0 = (const float*)d_in[1];
    const float* h1 = (const float*)d_in[2];
    const float* w  = (const float*)d_in[3];
    float* out = (float*)d_out;

    const int nblocks = (out_size / L_) * NT;   // B*C*NT = 2048 blocks of 512
    cmrc_kernel<<<nblocks, BLK, 0, stream>>>(x, h0, h1, w, out);
}